// Round 6
// baseline (444.031 us; speedup 1.0000x reference)
//
#include <hip/hip_runtime.h>
#include <hip/hip_fp16.h>
#include <math.h>

typedef unsigned short u16;
typedef _Float16 f16x8 __attribute__((ext_vector_type(8)));
typedef float f32x4 __attribute__((ext_vector_type(4)));

#define HWp 4096
#define Cc 96
#define Bb 4
#define Oo 192
#define C3 288

// ---------- fp32 workspace region (float offsets) ----------
#define OFF_WDWT  0           // [3][49][96]
#define OFF_BCAT  14112       // [192]
#define OFF_SBR   14304       // [288]
#define OFF_HBR   14592       // [288]
#define OFF_SPW   14880       // [192]
#define OFF_HPW   15072       // [192]
#define FP32_END  15264
// ---------- f16 region (u16 offsets, base = ws + FP32_END) ----------
#define BF_XTPAD  0           // [4][66][66][96]
#define BF_WOF    1672704     // 12 frag x 27 step x 64 lane x 8
#define BF_WPW    1838592     // 12 frag x 9 step x 64 lane x 8

__device__ __forceinline__ u16 f2h(float f) { return __half_as_ushort(__float2half(f)); }
__device__ __forceinline__ unsigned h2u(__half2 h) { union { __half2 h; unsigned u; } t; t.h = h; return t.u; }
__device__ __forceinline__ __half2 u2h(unsigned u) { union { __half2 h; unsigned u; } t; t.u = u; return t.h; }

#define PREP_N (165888 + 55296 + 14112 + 192 + 288 + 288 + 192 + 192 + 24960)
#define PREP_BLK ((PREP_N + 255) / 256)

// ---------------- prep + xtpad merged ----------------
__global__ __launch_bounds__(256) void prep_kernel(
    const float* __restrict__ x,
    const float* __restrict__ w3, const float* __restrict__ b3, const float* __restrict__ dw3,
    const float* __restrict__ g3, const float* __restrict__ be3, const float* __restrict__ m3, const float* __restrict__ v3,
    const float* __restrict__ w5, const float* __restrict__ b5, const float* __restrict__ dw5,
    const float* __restrict__ g5, const float* __restrict__ be5, const float* __restrict__ m5, const float* __restrict__ v5,
    const float* __restrict__ w7, const float* __restrict__ b7, const float* __restrict__ dw7,
    const float* __restrict__ g7, const float* __restrict__ be7, const float* __restrict__ m7, const float* __restrict__ v7,
    const float* __restrict__ wpw,
    const float* __restrict__ gp, const float* __restrict__ bp, const float* __restrict__ mp, const float* __restrict__ vp,
    float* __restrict__ ws)
{
    __shared__ u16 sT[64 * 104];
    u16* bf = (u16*)(ws + FP32_END);
    const int tid = threadIdx.x;

    if (blockIdx.x < 256) {                 // ---- xtpad interior ----
        const int b = blockIdx.x >> 6, h = blockIdx.x & 63;
        const float* xb = x + (((size_t)b * Cc) << 12) + (h << 6);
#pragma unroll
        for (int it = 0; it < 24; ++it) {
            int j = tid + it * 256;
            int c = j >> 6, p = j & 63;
            sT[p * 104 + c] = f2h(xb[((size_t)c << 12) + p]);
        }
        __syncthreads();
        u16* dst = bf + BF_XTPAD + ((size_t)(b * 66 + h + 1) * 66 + 1) * 96;
#pragma unroll
        for (int it = 0; it < 6; ++it) {
            int j = tid + it * 256;
            int pos = j / 24, c4 = j % 24;
            const u16* s = &sT[pos * 104 + c4 * 4];
            *(uint2*)(dst + pos * 96 + c4 * 4) = make_uint2(
                (unsigned)s[0] | ((unsigned)s[1] << 16),
                (unsigned)s[2] | ((unsigned)s[3] << 16));
        }
        return;
    }

    int i = (blockIdx.x - 256) * 256 + tid;
    if (i < 165888) {                       // WOF frag-linear f16
        int f = i / 13824, r = i % 13824;
        int s = r >> 9, l = r & 511;
        int lane = l >> 3, j = l & 7;
        int o = f * 16 + (lane & 15);
        int k = s * 32 + (lane >> 4) * 8 + j;
        int tap = k / 96, c = k % 96;
        float v = 0.f;
        if (o < 18)       v = w3[o * 864 + c * 9 + tap];
        else if (o < 68)  v = w5[(o - 18) * 864 + c * 9 + tap];
        else if (o < 166) v = w7[(o - 68) * 864 + c * 9 + tap];
        bf[BF_WOF + i] = f2h(v);
        return;
    }
    int j = i - 165888;
    if (j < 55296) {                        // WPW frag-linear f16
        int f = j / 4608, r = j % 4608;
        int s = r >> 9, l = r & 511;
        int lane = l >> 3, jj = l & 7;
        int o = f * 16 + (lane & 15);
        int k = s * 32 + (lane >> 4) * 8 + jj;
        bf[BF_WPW + j] = f2h(wpw[o * C3 + k]);
        return;
    }
    j -= 55296;
    if (j < 14112) {                        // wdwT [3][49][96] fp32
        int ksel = j / 4704, rem = j % 4704;
        int t = rem / 96, c = rem % 96;
        int K2 = (ksel == 0) ? 9 : (ksel == 1) ? 25 : 49;
        const float* dw = (ksel == 0) ? dw3 : (ksel == 1) ? dw5 : dw7;
        ws[OFF_WDWT + j] = (t < K2) ? dw[c * K2 + t] : 0.f;
        return;
    }
    j -= 14112;
    if (j < 192) {                          // bcat
        float v = 0.f;
        if (j < 18)       v = b3[j];
        else if (j < 68)  v = b5[j - 18];
        else if (j < 166) v = b7[j - 68];
        ws[OFF_BCAT + j] = v;
        return;
    }
    j -= 192;
    if (j < C3) {                           // sbr
        int ks = j / Cc, c = j % Cc;
        const float* g = (ks == 0) ? g3 : (ks == 1) ? g5 : g7;
        const float* v = (ks == 0) ? v3 : (ks == 1) ? v5 : v7;
        ws[OFF_SBR + j] = g[c] / sqrtf(v[c] + 1e-5f);
        return;
    }
    j -= C3;
    if (j < C3) {                           // hbr
        int ks = j / Cc, c = j % Cc;
        const float* g = (ks == 0) ? g3 : (ks == 1) ? g5 : g7;
        const float* v = (ks == 0) ? v3 : (ks == 1) ? v5 : v7;
        const float* be = (ks == 0) ? be3 : (ks == 1) ? be5 : be7;
        const float* m = (ks == 0) ? m3 : (ks == 1) ? m5 : m7;
        float inv = g[c] / sqrtf(v[c] + 1e-5f);
        ws[OFF_HBR + j] = be[c] - m[c] * inv;
        return;
    }
    j -= C3;
    if (j < Oo) { ws[OFF_SPW + j] = gp[j] / sqrtf(vp[j] + 1e-5f); return; }
    j -= Oo;
    if (j < Oo) {
        float inv = gp[j] / sqrtf(vp[j] + 1e-5f);
        ws[OFF_HPW + j] = bp[j] - mp[j] * inv;
        return;
    }
    j -= Oo;
    if (j < 24960) {                        // halo zero
        int c4 = j % 24, rem = j / 24;
        int cell = rem % 260, bb = rem / 260;
        int row, col;
        if (cell < 66)       { row = 0;  col = cell; }
        else if (cell < 132) { row = 65; col = cell - 66; }
        else if (cell < 196) { row = cell - 132 + 1; col = 0; }
        else                 { row = cell - 196 + 1; col = 65; }
        u16* dst = bf + BF_XTPAD + ((size_t)(bb * 66 + row) * 66 + col) * 96 + c4 * 4;
        *(uint2*)dst = make_uint2(0u, 0u);
        return;
    }
}

// ---------------- mega kernel ----------------
// Round 6: phase-4 gather traffic cut 18x via LDS rolling-window staging.
// Diagnosis (r0=r3=r5 at ~73 us despite chain 83->66 and VGPR 64->52): phase 4 is
// gather-TRAFFIC bound (1.02 MB L2 reads/block = 29x re-read of a 35 KB window;
// 4 blocks x 35 KB thrash the 32 KB L1). Fix: ky-major tap order (-3..3) + 3-row
// LDS ring (27 cols x 208 B-padded pixels); each image row loaded from L2 once.
// Out-of-window taps (|offset|>=1 or edge clamp) take an exact global fallback,
// so correctness never depends on the offset distribution.
// LDS: shA 11,232 (sX / tables wy,wx+coords) + regB 12,288 + ring 16,848 = 40,368
// -> still 4 blocks/CU. Accs (3x8 f32) live across '#pragma unroll 1' ky loop with
// <=15-tap bodies (small hoist window; r4's spill was a 49-tap unroll).
#define RING_COLS 27
#define RING_PSTR 208
#define RING_SLOT (RING_COLS * RING_PSTR)   // 5616
__global__ __launch_bounds__(256, 4) void mega_kernel(
    const float* __restrict__ ws, float* __restrict__ out)
{
    __shared__ __align__(16) unsigned char shA[11232];   // sX / {sWxy, sPk2}
    __shared__ float regB[3072];                         // soff / ytile
    __shared__ __align__(16) unsigned char ring[3 * RING_SLOT];  // 16848 B
    u16* sX = (u16*)shA;
    unsigned* sWxy = (unsigned*)shA;                     // [1328] (wy,wx) half2
    u16* sPk2 = (u16*)(shA + 5312);                      // [1328] y0p | x0p<<7
    float* soff = regB;
    u16* ytile = (u16*)regB;

    const u16* bf = (const u16*)(ws + FP32_END);
    const u16* xp = bf + BF_XTPAD;
    const int tid = threadIdx.x;
    const int lane = tid & 63, wid = tid >> 6;
    const int lane15 = lane & 15, quad = lane >> 4;

    // XCD-aware swizzle: 1024 blocks -> (batch, tile)
    const int bx = blockIdx.x;
    const int xcd = bx & 7;
    const int b = xcd >> 1;
    const int tile = ((bx >> 3) << 1) + (xcd & 1);
    const int p0 = tile * 16;
    const int h = p0 >> 6;                 // image row
    const int w0 = p0 & 63;                // start col (0/16/32/48)
    const int cb0 = w0 - 4;                // padded col of ring col 0

    const char* xbb = (const char*)(xp + (size_t)b * 66 * 66 * 96);

    // ---- phase 1a: load 3-row x 18-col patch into sX ----
    {
        const u16* src = xp + ((size_t)(b * 66 + h) * 66 + w0) * 96;
        for (int j = tid; j < 1296; j += 256) {
            int r = j / 432;
            int rem = j % 432;
            int col = rem / 24, c4 = rem % 24;
            uint2 v = *(const uint2*)(src + ((size_t)(r * 66 + col)) * 96 + c4 * 4);
            *(uint2*)(&sX[(r * 18 + col) * 104 + c4 * 4]) = v;
        }
    }
    // ---- phase 1b: ring prologue -- stage padded rows h-3..h-1 (window for ky=-3) ----
    {
#pragma unroll
        for (int r = 0; r < 3; ++r) {
            const int rp = h - 3 + r;
            const int base = (rp * 66 + cb0) * 192;
            const int sl = ((rp + 3) % 3) * RING_SLOT;
            for (int j = tid; j < 324; j += 256) {
                *(uint4*)(ring + sl + (j / 12) * RING_PSTR + (j % 12) * 16) =
                    *(const uint4*)(xbb + base + (j / 12) * 192 + (j % 12) * 16);
            }
        }
    }
    __syncthreads();

    // ---- phase 2: offset conv MFMA (M=192 as 12 frags / 4 waves, N=16, K=864) ----
    {
        const u16* wof = bf + BF_WOF;
        f32x4 acc[3];
#pragma unroll
        for (int ff = 0; ff < 3; ++ff) acc[ff] = (f32x4){0.f, 0.f, 0.f, 0.f};
#pragma unroll
        for (int tap = 0; tap < 9; ++tap) {
            const int ky2 = tap / 3, kx2 = tap % 3;
            const u16* brow = &sX[(ky2 * 18 + kx2 + lane15) * 104 + quad * 8];
#pragma unroll
            for (int cc = 0; cc < 3; ++cc) {
                f16x8 bb = *(const f16x8*)(brow + cc * 32);
                const int s = tap * 3 + cc;
#pragma unroll
                for (int ff = 0; ff < 3; ++ff) {
                    const int f = wid * 3 + ff;
                    f16x8 a = *(const f16x8*)(wof + ((size_t)(f * 27 + s) * 64 + lane) * 8);
                    acc[ff] = __builtin_amdgcn_mfma_f32_16x16x32_f16(a, bb, acc[ff], 0, 0, 0);
                }
            }
        }
        const float* bcat = ws + OFF_BCAT;
#pragma unroll
        for (int ff = 0; ff < 3; ++ff) {
#pragma unroll
            for (int r = 0; r < 4; ++r) {
                int co = (wid * 3 + ff) * 16 + quad * 4 + r;
                soff[co * 16 + lane15] = acc[ff][r] + bcat[co];
            }
        }
    }
    __syncthreads();   // sX reads done; soff complete

    // ---- phase 3: (wy,wx) + packed coords per (tap,pos) -> sWxy/sPk2 (clobbers sX) ----
    for (int i = tid; i < 1328; i += 256) {
        int gt = i >> 4, q = i & 15;
        int K, K2, R, tb, t;
        if (gt < 9)       { K = 3; K2 = 9;  R = 1; tb = 0;  t = gt; }
        else if (gt < 34) { K = 5; K2 = 25; R = 2; tb = 18; t = gt - 9; }
        else              { K = 7; K2 = 49; R = 3; tb = 68; t = gt - 34; }
        int ky = t / K - R, kx = t % K - R;
        float dy = soff[(tb + t) * 16 + q];
        float dx = soff[(tb + K2 + t) * 16 + q];
        float py = fminf(fmaxf((float)(h + ky) + dy, 0.f), 63.f);
        float px = fminf(fmaxf((float)(w0 + q + kx) + dx, 0.f), 63.f);
        float fy = floorf(py), fx = floorf(px);
        int y0 = (int)fy, x0 = (int)fx;
        float wy = py - fy, wx = px - fx;
        sWxy[i] = h2u(__floats2half2_rn(wy, wx));
        sPk2[i] = (u16)((y0 + 1) | ((x0 + 1) << 7));
    }
    __syncthreads();   // soff consumed; tables ready

    // ---- phase 4: ky-major gather (LDS ring + rare global fallback) + depthwise ----
#define TAPL(ACC, GT, WDP) { \
    const unsigned pk = sPk2[((GT) << 4) + q]; \
    const unsigned wxy = sWxy[((GT) << 4) + q]; \
    const int y0p = (int)(pk & 127u), x0p = (int)(pk >> 7); \
    const int rel = y0p - rowp; \
    const int cl  = x0p - cb0; \
    uint4 u00, u01, u10, u11; \
    if (((unsigned)rel <= 1u) && ((unsigned)cl <= 25u)) { \
        int s0 = bs + rel; s0 = (s0 >= 3) ? s0 - 3 : s0; \
        int s1 = s0 + 1;   s1 = (s1 >= 3) ? s1 - 3 : s1; \
        const unsigned char* p0 = ring + s0 * RING_SLOT + cl * RING_PSTR + c8off; \
        const unsigned char* p1 = ring + s1 * RING_SLOT + cl * RING_PSTR + c8off; \
        u00 = *(const uint4*)(p0); u01 = *(const uint4*)(p0 + RING_PSTR); \
        u10 = *(const uint4*)(p1); u11 = *(const uint4*)(p1 + RING_PSTR); \
    } else { \
        const char* pb = xbb + (y0p * 66 + x0p) * 192 + c8off; \
        u00 = *(const uint4*)(pb); u01 = *(const uint4*)(pb + 192); \
        u10 = *(const uint4*)(pb + 12672); u11 = *(const uint4*)(pb + 12864); \
    } \
    const __half2 wyx = u2h(wxy); \
    const __half wyh = __low2half(wyx), wxh = __high2half(wyx); \
    const __half h11 = __hmul(wyh, wxh); \
    const __half h10 = __hsub(wyh, h11); \
    const __half h01 = __hsub(wxh, h11); \
    const __half h00 = __hsub(__hsub(__ushort_as_half((unsigned short)0x3C00), wyh), h01); \
    const __half2 w00b = __half2half2(h00), w01b = __half2half2(h01); \
    const __half2 w10b = __half2half2(h10), w11b = __half2half2(h11); \
    const float4 wda = *(const float4*)(WDP); \
    const float4 wdb = *(const float4*)((WDP) + 4); \
    const unsigned a00[4] = {u00.x, u00.y, u00.z, u00.w}; \
    const unsigned a01[4] = {u01.x, u01.y, u01.z, u01.w}; \
    const unsigned a10[4] = {u10.x, u10.y, u10.z, u10.w}; \
    const unsigned a11[4] = {u11.x, u11.y, u11.z, u11.w}; \
    const float wd8[8] = {wda.x, wda.y, wda.z, wda.w, wdb.x, wdb.y, wdb.z, wdb.w}; \
    _Pragma("unroll") \
    for (int d = 0; d < 4; ++d) { \
        __half2 v = __hmul2(w00b, u2h(a00[d])); \
        v = __hfma2(w01b, u2h(a01[d]), v); \
        v = __hfma2(w10b, u2h(a10[d]), v); \
        v = __hfma2(w11b, u2h(a11[d]), v); \
        ACC[2 * d]     = fmaf(wd8[2 * d],     __low2float(v),  ACC[2 * d]); \
        ACC[2 * d + 1] = fmaf(wd8[2 * d + 1], __high2float(v), ACC[2 * d + 1]); \
    } }

#define BN_STORE(ACC, CB, Q) { \
    const float4 sa = *(const float4*)(ws + OFF_SBR + (CB)); \
    const float4 sb = *(const float4*)(ws + OFF_SBR + (CB) + 4); \
    const float4 ha = *(const float4*)(ws + OFF_HBR + (CB)); \
    const float4 hb = *(const float4*)(ws + OFF_HBR + (CB) + 4); \
    const float ss8[8] = {sa.x, sa.y, sa.z, sa.w, sb.x, sb.y, sb.z, sb.w}; \
    const float hh8[8] = {ha.x, ha.y, ha.z, ha.w, hb.x, hb.y, hb.z, hb.w}; \
    unsigned rr[4]; \
    _Pragma("unroll") \
    for (int d = 0; d < 4; ++d) { \
        float lo = fmaxf(fmaf(ACC[2 * d],     ss8[2 * d],     hh8[2 * d]),     0.f); \
        float hi = fmaxf(fmaf(ACC[2 * d + 1], ss8[2 * d + 1], hh8[2 * d + 1]), 0.f); \
        rr[d] = h2u(__floats2half2_rn(lo, hi)); \
    } \
    *(uint4*)(ytile + (Q) * 296 + (CB)) = make_uint4(rr[0], rr[1], rr[2], rr[3]); }

    {
        const int c8 = tid % 12;
        const int q  = tid / 12;            // valid for tid<192
        const int c8off = c8 * 16;
        const float* wd0 = ws + OFF_WDWT + c8 * 8;
        const float* wd1 = ws + OFF_WDWT + 4704 + c8 * 8;
        const float* wd2 = ws + OFF_WDWT + 9408 + c8 * 8;
        float accA[8] = {0.f, 0.f, 0.f, 0.f, 0.f, 0.f, 0.f, 0.f};
        float accB[8] = {0.f, 0.f, 0.f, 0.f, 0.f, 0.f, 0.f, 0.f};
        float accC[8] = {0.f, 0.f, 0.f, 0.f, 0.f, 0.f, 0.f, 0.f};

#pragma unroll 1
        for (int kyi = 0; kyi < 7; ++kyi) {
            const int ky = kyi - 3;
            const int rowp = h + ky;             // y0p base of this window
            const int bs = (h + kyi) % 3;        // slot of row rowp ( == (rowp+3)%3 )

            // T14: issue next row's loads early (row h+kyi, goes into freed slot bs)
            uint4 st0, st1;
            if (kyi < 6) {
                const int base = ((h + kyi) * 66 + cb0) * 192;
                st0 = *(const uint4*)(xbb + base + (tid / 12) * 192 + (tid % 12) * 16);
                if (tid < 68) {
                    const int j2 = tid + 256;
                    st1 = *(const uint4*)(xbb + base + (j2 / 12) * 192 + (j2 % 12) * 16);
                }
            }

            if (tid < 192) {
                if (ky >= -1 && ky <= 1) {       // seg0 (3x3)
                    const int t0 = (ky + 1) * 3;
#pragma unroll
                    for (int j = 0; j < 3; ++j)
                        TAPL(accA, t0 + j, wd0 + (t0 + j) * 96);
                }
                if (ky >= -2 && ky <= 2) {       // seg1 (5x5)
                    const int t1 = (ky + 2) * 5;
#pragma unroll
                    for (int j = 0; j < 5; ++j)
                        TAPL(accB, 9 + t1 + j, wd1 + (t1 + j) * 96);
                }
                {                                // seg2 (7x7)
                    const int t2 = (ky + 3) * 7;
#pragma unroll
                    for (int j = 0; j < 7; ++j)
                        TAPL(accC, 34 + t2 + j, wd2 + (t2 + j) * 96);
                }
            }

            if (kyi < 6) {
                __syncthreads();                 // ring reads of slot bs done
                const int sl = bs * RING_SLOT;
                *(uint4*)(ring + sl + (tid / 12) * RING_PSTR + (tid % 12) * 16) = st0;
                if (tid < 68) {
                    const int j2 = tid + 256;
                    *(uint4*)(ring + sl + (j2 / 12) * RING_PSTR + (j2 % 12) * 16) = st1;
                }
                __syncthreads();                 // new row visible
            }
        }

        if (tid < 192) {
            const int c = c8 * 8;
            BN_STORE(accA, c, q);
            BN_STORE(accB, 96 + c, q);
            BN_STORE(accC, 192 + c, q);
        }
    }
    __syncthreads();   // ytile ready

    // ---- phase 5: pointwise MFMA (M=192 as 12 frags / 4 waves, N=16, K=288) + BN + ReLU ----
    {
        const u16* wpw = bf + BF_WPW;
        f32x4 acc[3];
#pragma unroll
        for (int ff = 0; ff < 3; ++ff) acc[ff] = (f32x4){0.f, 0.f, 0.f, 0.f};
        const u16* brow = &ytile[lane15 * 296 + quad * 8];
#pragma unroll
        for (int s = 0; s < 9; ++s) {
            f16x8 bb = *(const f16x8*)(brow + s * 32);
#pragma unroll
            for (int ff = 0; ff < 3; ++ff) {
                const int f = wid * 3 + ff;
                f16x8 a = *(const f16x8*)(wpw + ((size_t)(f * 9 + s) * 64 + lane) * 8);
                acc[ff] = __builtin_amdgcn_mfma_f32_16x16x32_f16(a, bb, acc[ff], 0, 0, 0);
            }
        }
        const float* spw = ws + OFF_SPW;
        const float* hpw = ws + OFF_HPW;
        const int p = p0 + lane15;
#pragma unroll
        for (int ff = 0; ff < 3; ++ff) {
#pragma unroll
            for (int r = 0; r < 4; ++r) {
                int o = (wid * 3 + ff) * 16 + quad * 4 + r;
                out[(((size_t)(b * Oo + o)) << 12) + p] =
                    fmaxf(fmaf(acc[ff][r], spw[o], hpw[o]), 0.f);
            }
        }
    }
}

extern "C" void kernel_launch(void* const* d_in, const int* in_sizes, int n_in,
                              void* d_out, int out_size, void* d_ws, size_t ws_size,
                              hipStream_t stream)
{
    const float* x     = (const float*)d_in[0];
    const float* w3    = (const float*)d_in[1];
    const float* b3    = (const float*)d_in[2];
    const float* dw3   = (const float*)d_in[3];
    const float* g3    = (const float*)d_in[4];
    const float* be3   = (const float*)d_in[5];
    const float* m3    = (const float*)d_in[6];
    const float* v3    = (const float*)d_in[7];
    const float* w5    = (const float*)d_in[8];
    const float* b5    = (const float*)d_in[9];
    const float* dw5   = (const float*)d_in[10];
    const float* g5    = (const float*)d_in[11];
    const float* be5   = (const float*)d_in[12];
    const float* m5    = (const float*)d_in[13];
    const float* v5    = (const float*)d_in[14];
    const float* w7    = (const float*)d_in[15];
    const float* b7    = (const float*)d_in[16];
    const float* dw7   = (const float*)d_in[17];
    const float* g7    = (const float*)d_in[18];
    const float* be7   = (const float*)d_in[19];
    const float* m7    = (const float*)d_in[20];
    const float* v7    = (const float*)d_in[21];
    const float* wpw   = (const float*)d_in[22];
    const float* gp    = (const float*)d_in[23];
    const float* bp    = (const float*)d_in[24];
    const float* mp    = (const float*)d_in[25];
    const float* vp    = (const float*)d_in[26];

    float* ws = (float*)d_ws;
    float* out = (float*)d_out;

    {   // 1) prep + xtpad (merged)
        prep_kernel<<<256 + PREP_BLK, 256, 0, stream>>>(
            x,
            w3, b3, dw3, g3, be3, m3, v3,
            w5, b5, dw5, g5, be5, m5, v5,
            w7, b7, dw7, g7, be7, m7, v7,
            wpw, gp, bp, mp, vp, ws);
    }
    {   // 2) fully fused pipeline, XCD-swizzled 1-D grid
        mega_kernel<<<1024, 256, 0, stream>>>(ws, out);
    }
}

// Round 7
// 217.616 us; speedup vs baseline: 2.0404x; 2.0404x over previous
//
#include <hip/hip_runtime.h>
#include <hip/hip_fp16.h>
#include <math.h>

typedef unsigned short u16;
typedef _Float16 f16x8 __attribute__((ext_vector_type(8)));
typedef float f32x4 __attribute__((ext_vector_type(4)));

#define HWp 4096
#define Cc 96
#define Bb 4
#define Oo 192
#define C3 288

// ---------- fp32 workspace region (float offsets) ----------
#define OFF_WDWT  0           // [3][49][96]
#define OFF_BCAT  14112       // [192]
#define OFF_SBR   14304       // [288]
#define OFF_HBR   14592       // [288]
#define OFF_SPW   14880       // [192]
#define OFF_HPW   15072       // [192]
#define FP32_END  15264
// ---------- f16 region (u16 offsets, base = ws + FP32_END) ----------
#define BF_XTPAD  0           // [4][66][66][96]
#define BF_WOF    1672704     // 12 frag x 27 step x 64 lane x 8
#define BF_WPW    1838592     // 12 frag x 9 step x 64 lane x 8

__device__ __forceinline__ u16 f2h(float f) { return __half_as_ushort(__float2half(f)); }
__device__ __forceinline__ unsigned h2u(__half2 h) { union { __half2 h; unsigned u; } t; t.h = h; return t.u; }
__device__ __forceinline__ __half2 u2h(unsigned u) { union { __half2 h; unsigned u; } t; t.u = u; return t.h; }

#define PREP_N (165888 + 55296 + 14112 + 192 + 288 + 288 + 192 + 192 + 24960)
#define PREP_BLK ((PREP_N + 255) / 256)

// ---------------- prep + xtpad merged ----------------
__global__ __launch_bounds__(256) void prep_kernel(
    const float* __restrict__ x,
    const float* __restrict__ w3, const float* __restrict__ b3, const float* __restrict__ dw3,
    const float* __restrict__ g3, const float* __restrict__ be3, const float* __restrict__ m3, const float* __restrict__ v3,
    const float* __restrict__ w5, const float* __restrict__ b5, const float* __restrict__ dw5,
    const float* __restrict__ g5, const float* __restrict__ be5, const float* __restrict__ m5, const float* __restrict__ v5,
    const float* __restrict__ w7, const float* __restrict__ b7, const float* __restrict__ dw7,
    const float* __restrict__ g7, const float* __restrict__ be7, const float* __restrict__ m7, const float* __restrict__ v7,
    const float* __restrict__ wpw,
    const float* __restrict__ gp, const float* __restrict__ bp, const float* __restrict__ mp, const float* __restrict__ vp,
    float* __restrict__ ws)
{
    __shared__ u16 sT[64 * 104];
    u16* bf = (u16*)(ws + FP32_END);
    const int tid = threadIdx.x;

    if (blockIdx.x < 256) {                 // ---- xtpad interior ----
        const int b = blockIdx.x >> 6, h = blockIdx.x & 63;
        const float* xb = x + (((size_t)b * Cc) << 12) + (h << 6);
#pragma unroll
        for (int it = 0; it < 24; ++it) {
            int j = tid + it * 256;
            int c = j >> 6, p = j & 63;
            sT[p * 104 + c] = f2h(xb[((size_t)c << 12) + p]);
        }
        __syncthreads();
        u16* dst = bf + BF_XTPAD + ((size_t)(b * 66 + h + 1) * 66 + 1) * 96;
#pragma unroll
        for (int it = 0; it < 6; ++it) {
            int j = tid + it * 256;
            int pos = j / 24, c4 = j % 24;
            const u16* s = &sT[pos * 104 + c4 * 4];
            *(uint2*)(dst + pos * 96 + c4 * 4) = make_uint2(
                (unsigned)s[0] | ((unsigned)s[1] << 16),
                (unsigned)s[2] | ((unsigned)s[3] << 16));
        }
        return;
    }

    int i = (blockIdx.x - 256) * 256 + tid;
    if (i < 165888) {                       // WOF frag-linear f16
        int f = i / 13824, r = i % 13824;
        int s = r >> 9, l = r & 511;
        int lane = l >> 3, j = l & 7;
        int o = f * 16 + (lane & 15);
        int k = s * 32 + (lane >> 4) * 8 + j;
        int tap = k / 96, c = k % 96;
        float v = 0.f;
        if (o < 18)       v = w3[o * 864 + c * 9 + tap];
        else if (o < 68)  v = w5[(o - 18) * 864 + c * 9 + tap];
        else if (o < 166) v = w7[(o - 68) * 864 + c * 9 + tap];
        bf[BF_WOF + i] = f2h(v);
        return;
    }
    int j = i - 165888;
    if (j < 55296) {                        // WPW frag-linear f16
        int f = j / 4608, r = j % 4608;
        int s = r >> 9, l = r & 511;
        int lane = l >> 3, jj = l & 7;
        int o = f * 16 + (lane & 15);
        int k = s * 32 + (lane >> 4) * 8 + jj;
        bf[BF_WPW + j] = f2h(wpw[o * C3 + k]);
        return;
    }
    j -= 55296;
    if (j < 14112) {                        // wdwT [3][49][96] fp32
        int ksel = j / 4704, rem = j % 4704;
        int t = rem / 96, c = rem % 96;
        int K2 = (ksel == 0) ? 9 : (ksel == 1) ? 25 : 49;
        const float* dw = (ksel == 0) ? dw3 : (ksel == 1) ? dw5 : dw7;
        ws[OFF_WDWT + j] = (t < K2) ? dw[c * K2 + t] : 0.f;
        return;
    }
    j -= 14112;
    if (j < 192) {                          // bcat
        float v = 0.f;
        if (j < 18)       v = b3[j];
        else if (j < 68)  v = b5[j - 18];
        else if (j < 166) v = b7[j - 68];
        ws[OFF_BCAT + j] = v;
        return;
    }
    j -= 192;
    if (j < C3) {                           // sbr
        int ks = j / Cc, c = j % Cc;
        const float* g = (ks == 0) ? g3 : (ks == 1) ? g5 : g7;
        const float* v = (ks == 0) ? v3 : (ks == 1) ? v5 : v7;
        ws[OFF_SBR + j] = g[c] / sqrtf(v[c] + 1e-5f);
        return;
    }
    j -= C3;
    if (j < C3) {                           // hbr
        int ks = j / Cc, c = j % Cc;
        const float* g = (ks == 0) ? g3 : (ks == 1) ? g5 : g7;
        const float* v = (ks == 0) ? v3 : (ks == 1) ? v5 : v7;
        const float* be = (ks == 0) ? be3 : (ks == 1) ? be5 : be7;
        const float* m = (ks == 0) ? m3 : (ks == 1) ? m5 : m7;
        float inv = g[c] / sqrtf(v[c] + 1e-5f);
        ws[OFF_HBR + j] = be[c] - m[c] * inv;
        return;
    }
    j -= C3;
    if (j < Oo) { ws[OFF_SPW + j] = gp[j] / sqrtf(vp[j] + 1e-5f); return; }
    j -= Oo;
    if (j < Oo) {
        float inv = gp[j] / sqrtf(vp[j] + 1e-5f);
        ws[OFF_HPW + j] = bp[j] - mp[j] * inv;
        return;
    }
    j -= Oo;
    if (j < 24960) {                        // halo zero
        int c4 = j % 24, rem = j / 24;
        int cell = rem % 260, bb = rem / 260;
        int row, col;
        if (cell < 66)       { row = 0;  col = cell; }
        else if (cell < 132) { row = 65; col = cell - 66; }
        else if (cell < 196) { row = cell - 132 + 1; col = 0; }
        else                 { row = cell - 196 + 1; col = 65; }
        u16* dst = bf + BF_XTPAD + ((size_t)(bb * 66 + row) * 66 + col) * 96 + c4 * 4;
        *(uint2*)dst = make_uint2(0u, 0u);
        return;
    }
}

// ---------------- mega kernel ----------------
// Round 7: stationary 9x24-pixel LDS window (44,928 B, 208 B/pixel stride ->
// 16-aligned b128 reads, 2-way-free bank pattern). With |offset|<1 (sigma~0.29)
// every tap's 4 bilinear neighbors are in-window: slot=y0p-h+3 in [0,8],
// cell=x0p-w0+3 in [0,23]. Phase 3 classifies once per (tap,q): in-window ->
// u16 = ldsbyte/16; else flag|y0p|x0p -> exact per-lane global fallback.
// Phase 4 keeps r5's spill-free shape (3 flat seg loops, ONE acc[8] live).
// Window replaces sX: phase 2 reads B-fragments from it (same 104-u16 pixel
// stride). No ring, no rolling, no mid-phase barriers (r6's failure modes).
// LDS 65,184 B -> 2 blocks/CU (deliberate: phase 4 becomes LDS-pipe bound,
// ~10 us vs ~55 us VMEM). launch_bounds(256,2) -> 256-VGPR budget, no spill.
#define WIN_PSTR 208
#define WIN_RSTR (24 * WIN_PSTR)       // 4992
__global__ __launch_bounds__(256, 2) void mega_kernel(
    const float* __restrict__ ws, float* __restrict__ out)
{
    __shared__ __align__(16) unsigned char win[9 * WIN_RSTR];  // 44,928 B
    __shared__ unsigned sWxy[1328];                            // 5,312 B (wy,wx) half2
    __shared__ u16 sPk[1328];                                  // 2,656 B
    __shared__ float regB[3072];                               // 12,288 B: soff / ytile
    float* soff = regB;
    u16* ytile = (u16*)regB;

    const u16* bf = (const u16*)(ws + FP32_END);
    const u16* xp = bf + BF_XTPAD;
    const int tid = threadIdx.x;
    const int lane = tid & 63, wid = tid >> 6;
    const int lane15 = lane & 15, quad = lane >> 4;

    // XCD-aware swizzle: 1024 blocks -> (batch, tile)
    const int bx = blockIdx.x;
    const int xcd = bx & 7;
    const int b = xcd >> 1;
    const int tile = ((bx >> 3) << 1) + (xcd & 1);
    const int p0 = tile * 16;
    const int h = p0 >> 6;                 // image row
    const int w0 = p0 & 63;                // start col (0/16/32/48)

    const char* xbb = (const char*)(xp + (size_t)b * 66 * 66 * 96);

    // ---- phase 1: stage 9x24 padded-pixel window (rows h-3..h+5, cols w0-3..w0+20) ----
    for (int j = tid; j < 2592; j += 256) {          // 9*24*12 uint4
        int cell = j / 12, k = j - cell * 12;
        int r = cell / 24, c = cell - r * 24;
        int rr = h - 3 + r; rr = rr < 0 ? 0 : (rr > 65 ? 65 : rr);   // clamped cells never read
        int cc = w0 - 3 + c; cc = cc < 0 ? 0 : (cc > 65 ? 65 : cc);
        *(uint4*)(win + cell * WIN_PSTR + k * 16) =
            *(const uint4*)(xbb + (rr * 66 + cc) * 192 + k * 16);
    }
    __syncthreads();

    // ---- phase 2: offset conv MFMA (B-frags from win rows 3..5 = padded rows h..h+2) ----
    {
        const u16* wof = bf + BF_WOF;
        f32x4 acc[3];
#pragma unroll
        for (int ff = 0; ff < 3; ++ff) acc[ff] = (f32x4){0.f, 0.f, 0.f, 0.f};
#pragma unroll
        for (int tap = 0; tap < 9; ++tap) {
            const int ky2 = tap / 3, kx2 = tap % 3;
            const u16* brow = (const u16*)win +
                ((size_t)((3 + ky2) * 24 + 3 + kx2 + lane15)) * 104 + quad * 8;
#pragma unroll
            for (int cc = 0; cc < 3; ++cc) {
                f16x8 bb = *(const f16x8*)(brow + cc * 32);
                const int s = tap * 3 + cc;
#pragma unroll
                for (int ff = 0; ff < 3; ++ff) {
                    const int f = wid * 3 + ff;
                    f16x8 a = *(const f16x8*)(wof + ((size_t)(f * 27 + s) * 64 + lane) * 8);
                    acc[ff] = __builtin_amdgcn_mfma_f32_16x16x32_f16(a, bb, acc[ff], 0, 0, 0);
                }
            }
        }
        const float* bcat = ws + OFF_BCAT;
#pragma unroll
        for (int ff = 0; ff < 3; ++ff) {
#pragma unroll
            for (int r = 0; r < 4; ++r) {
                int co = (wid * 3 + ff) * 16 + quad * 4 + r;
                soff[co * 16 + lane15] = acc[ff][r] + bcat[co];
            }
        }
    }
    __syncthreads();   // win conv-reads done; soff complete

    // ---- phase 3: per-(tap,pos) weights + window-offset/fallback classification ----
    for (int i = tid; i < 1328; i += 256) {
        int gt = i >> 4, q = i & 15;
        int K, K2, R, tb, t;
        if (gt < 9)       { K = 3; K2 = 9;  R = 1; tb = 0;  t = gt; }
        else if (gt < 34) { K = 5; K2 = 25; R = 2; tb = 18; t = gt - 9; }
        else              { K = 7; K2 = 49; R = 3; tb = 68; t = gt - 34; }
        int ky = t / K - R, kx = t % K - R;
        float dy = soff[(tb + t) * 16 + q];
        float dx = soff[(tb + K2 + t) * 16 + q];
        float py = fminf(fmaxf((float)(h + ky) + dy, 0.f), 63.f);
        float px = fminf(fmaxf((float)(w0 + q + kx) + dx, 0.f), 63.f);
        float fy = floorf(py), fx = floorf(px);
        int y0 = (int)fy, x0 = (int)fx;
        float wy = py - fy, wx = px - fx;
        int y0p = y0 + 1, x0p = x0 + 1;           // padded coords
        int slot = y0p - h + 3;
        int cell = x0p - w0 + 3;
        unsigned pk;
        if ((unsigned)slot <= 7u && (unsigned)cell <= 22u)
            pk = (unsigned)((slot * 24 + cell) * 13);           // byte_off/16 (<2795)
        else
            pk = 0x8000u | ((unsigned)y0p << 7) | (unsigned)x0p; // rare fallback
        sWxy[i] = h2u(__floats2half2_rn(wy, wx));
        sPk[i] = (u16)pk;
    }
    __syncthreads();   // soff consumed; tables ready

    // ---- phase 4: LDS gather + depthwise + BN + ReLU -> ytile ----
#define TAPW(ACC, GT, WDP) { \
    const unsigned pk = sPk[((GT) << 4) + q]; \
    const unsigned wxy = sWxy[((GT) << 4) + q]; \
    uint4 u00, u01, u10, u11; \
    if (!(pk & 0x8000u)) { \
        const unsigned char* wb = win + pk * 16 + c8off; \
        u00 = *(const uint4*)(wb); \
        u01 = *(const uint4*)(wb + WIN_PSTR); \
        u10 = *(const uint4*)(wb + WIN_RSTR); \
        u11 = *(const uint4*)(wb + WIN_RSTR + WIN_PSTR); \
    } else { \
        const char* pb = xbb + (((int)((pk >> 7) & 127u)) * 66 + (int)(pk & 127u)) * 192 + c8off; \
        u00 = *(const uint4*)(pb);         u01 = *(const uint4*)(pb + 192); \
        u10 = *(const uint4*)(pb + 12672); u11 = *(const uint4*)(pb + 12864); \
    } \
    const __half2 wyx = u2h(wxy); \
    const __half wyh = __low2half(wyx), wxh = __high2half(wyx); \
    const __half h11 = __hmul(wyh, wxh); \
    const __half h10 = __hsub(wyh, h11); \
    const __half h01 = __hsub(wxh, h11); \
    const __half h00 = __hsub(__hsub(__ushort_as_half((unsigned short)0x3C00), wyh), h01); \
    const __half2 w00b = __half2half2(h00), w01b = __half2half2(h01); \
    const __half2 w10b = __half2half2(h10), w11b = __half2half2(h11); \
    const float4 wda = *(const float4*)(WDP); \
    const float4 wdb = *(const float4*)((WDP) + 4); \
    const unsigned a00[4] = {u00.x, u00.y, u00.z, u00.w}; \
    const unsigned a01[4] = {u01.x, u01.y, u01.z, u01.w}; \
    const unsigned a10[4] = {u10.x, u10.y, u10.z, u10.w}; \
    const unsigned a11[4] = {u11.x, u11.y, u11.z, u11.w}; \
    const float wd8[8] = {wda.x, wda.y, wda.z, wda.w, wdb.x, wdb.y, wdb.z, wdb.w}; \
    _Pragma("unroll") \
    for (int d = 0; d < 4; ++d) { \
        __half2 v = __hmul2(w00b, u2h(a00[d])); \
        v = __hfma2(w01b, u2h(a01[d]), v); \
        v = __hfma2(w10b, u2h(a10[d]), v); \
        v = __hfma2(w11b, u2h(a11[d]), v); \
        ACC[2 * d]     = fmaf(wd8[2 * d],     __low2float(v),  ACC[2 * d]); \
        ACC[2 * d + 1] = fmaf(wd8[2 * d + 1], __high2float(v), ACC[2 * d + 1]); \
    } }

#define BN_STORE(ACC, CB, Q) { \
    const float4 sa = *(const float4*)(ws + OFF_SBR + (CB)); \
    const float4 sb = *(const float4*)(ws + OFF_SBR + (CB) + 4); \
    const float4 ha = *(const float4*)(ws + OFF_HBR + (CB)); \
    const float4 hb = *(const float4*)(ws + OFF_HBR + (CB) + 4); \
    const float ss8[8] = {sa.x, sa.y, sa.z, sa.w, sb.x, sb.y, sb.z, sb.w}; \
    const float hh8[8] = {ha.x, ha.y, ha.z, ha.w, hb.x, hb.y, hb.z, hb.w}; \
    unsigned rr[4]; \
    _Pragma("unroll") \
    for (int d = 0; d < 4; ++d) { \
        float lo = fmaxf(fmaf(ACC[2 * d],     ss8[2 * d],     hh8[2 * d]),     0.f); \
        float hi = fmaxf(fmaf(ACC[2 * d + 1], ss8[2 * d + 1], hh8[2 * d + 1]), 0.f); \
        rr[d] = h2u(__floats2half2_rn(lo, hi)); \
    } \
    *(uint4*)(ytile + (Q) * 296 + (CB)) = make_uint4(rr[0], rr[1], rr[2], rr[3]); }

    if (tid < 192) {
        const int c8 = tid % 12;
        const int q  = tid / 12;            // 0..15
        const int c = c8 * 8;
        const int c8off = c8 * 16;

        {   // seg0 (3x3)
            float acc[8] = {0.f, 0.f, 0.f, 0.f, 0.f, 0.f, 0.f, 0.f};
            const float* wdT = ws + OFF_WDWT + c;
            for (int gt = 0; gt < 9; ++gt)
                TAPW(acc, gt, wdT + gt * 96);
            BN_STORE(acc, c, q);
        }
        {   // seg1 (5x5)
            float acc[8] = {0.f, 0.f, 0.f, 0.f, 0.f, 0.f, 0.f, 0.f};
            const float* wdT = ws + OFF_WDWT + 4704 + c;
            for (int gt = 9; gt < 34; ++gt)
                TAPW(acc, gt, wdT + (gt - 9) * 96);
            BN_STORE(acc, 96 + c, q);
        }
        {   // seg2 (7x7)
            float acc[8] = {0.f, 0.f, 0.f, 0.f, 0.f, 0.f, 0.f, 0.f};
            const float* wdT = ws + OFF_WDWT + 9408 + c;
            for (int gt = 34; gt < 83; ++gt)
                TAPW(acc, gt, wdT + (gt - 34) * 96);
            BN_STORE(acc, 192 + c, q);
        }
    }
    __syncthreads();   // ytile ready

    // ---- phase 5: pointwise MFMA (M=192 as 12 frags / 4 waves, N=16, K=288) + BN + ReLU ----
    {
        const u16* wpw = bf + BF_WPW;
        f32x4 acc[3];
#pragma unroll
        for (int ff = 0; ff < 3; ++ff) acc[ff] = (f32x4){0.f, 0.f, 0.f, 0.f};
        const u16* brow = &ytile[lane15 * 296 + quad * 8];
#pragma unroll
        for (int s = 0; s < 9; ++s) {
            f16x8 bb = *(const f16x8*)(brow + s * 32);
#pragma unroll
            for (int ff = 0; ff < 3; ++ff) {
                const int f = wid * 3 + ff;
                f16x8 a = *(const f16x8*)(wpw + ((size_t)(f * 9 + s) * 64 + lane) * 8);
                acc[ff] = __builtin_amdgcn_mfma_f32_16x16x32_f16(a, bb, acc[ff], 0, 0, 0);
            }
        }
        const float* spw = ws + OFF_SPW;
        const float* hpw = ws + OFF_HPW;
        const int p = p0 + lane15;
#pragma unroll
        for (int ff = 0; ff < 3; ++ff) {
#pragma unroll
            for (int r = 0; r < 4; ++r) {
                int o = (wid * 3 + ff) * 16 + quad * 4 + r;
                out[(((size_t)(b * Oo + o)) << 12) + p] =
                    fmaxf(fmaf(acc[ff][r], spw[o], hpw[o]), 0.f);
            }
        }
    }
}

extern "C" void kernel_launch(void* const* d_in, const int* in_sizes, int n_in,
                              void* d_out, int out_size, void* d_ws, size_t ws_size,
                              hipStream_t stream)
{
    const float* x     = (const float*)d_in[0];
    const float* w3    = (const float*)d_in[1];
    const float* b3    = (const float*)d_in[2];
    const float* dw3   = (const float*)d_in[3];
    const float* g3    = (const float*)d_in[4];
    const float* be3   = (const float*)d_in[5];
    const float* m3    = (const float*)d_in[6];
    const float* v3    = (const float*)d_in[7];
    const float* w5    = (const float*)d_in[8];
    const float* b5    = (const float*)d_in[9];
    const float* dw5   = (const float*)d_in[10];
    const float* g5    = (const float*)d_in[11];
    const float* be5   = (const float*)d_in[12];
    const float* m5    = (const float*)d_in[13];
    const float* v5    = (const float*)d_in[14];
    const float* w7    = (const float*)d_in[15];
    const float* b7    = (const float*)d_in[16];
    const float* dw7   = (const float*)d_in[17];
    const float* g7    = (const float*)d_in[18];
    const float* be7   = (const float*)d_in[19];
    const float* m7    = (const float*)d_in[20];
    const float* v7    = (const float*)d_in[21];
    const float* wpw   = (const float*)d_in[22];
    const float* gp    = (const float*)d_in[23];
    const float* bp    = (const float*)d_in[24];
    const float* mp    = (const float*)d_in[25];
    const float* vp    = (const float*)d_in[26];

    float* ws = (float*)d_ws;
    float* out = (float*)d_out;

    {   // 1) prep + xtpad (merged)
        prep_kernel<<<256 + PREP_BLK, 256, 0, stream>>>(
            x,
            w3, b3, dw3, g3, be3, m3, v3,
            w5, b5, dw5, g5, be5, m5, v5,
            w7, b7, dw7, g7, be7, m7, v7,
            wpw, gp, bp, mp, vp, ws);
    }
    {   // 2) fully fused pipeline, XCD-swizzled 1-D grid
        mega_kernel<<<1024, 256, 0, stream>>>(ws, out);
    }
}

// Round 8
// 177.705 us; speedup vs baseline: 2.4987x; 1.2246x over previous
//
#include <hip/hip_runtime.h>
#include <hip/hip_fp16.h>
#include <math.h>

typedef unsigned short u16;
typedef _Float16 f16x8 __attribute__((ext_vector_type(8)));
typedef float f32x4 __attribute__((ext_vector_type(4)));

#define HWp 4096
#define Cc 96
#define Bb 4
#define Oo 192
#define C3 288

// ---------- fp32 workspace region (float offsets) ----------
#define OFF_WDWT  0           // [3][49][96]
#define OFF_BCAT  14112       // [192]
#define OFF_SBR   14304       // [288]
#define OFF_HBR   14592       // [288]
#define OFF_SPW   14880       // [192]
#define OFF_HPW   15072       // [192]
#define FP32_END  15264
// ---------- f16 region (u16 offsets, base = ws + FP32_END) ----------
#define BF_XTPAD  0           // [4][66][66][96]
#define BF_WOF    1672704     // 12 frag x 27 step x 64 lane x 8
#define BF_WPW    1838592     // 12 frag x 9 step x 64 lane x 8

__device__ __forceinline__ u16 f2h(float f) { return __half_as_ushort(__float2half(f)); }
__device__ __forceinline__ unsigned h2u(__half2 h) { union { __half2 h; unsigned u; } t; t.h = h; return t.u; }
__device__ __forceinline__ __half2 u2h(unsigned u) { union { __half2 h; unsigned u; } t; t.u = u; return t.h; }

#define PREP_N (165888 + 55296 + 14112 + 192 + 288 + 288 + 192 + 192 + 24960)
#define PREP_BLK ((PREP_N + 255) / 256)

// ---------------- prep + xtpad merged ----------------
__global__ __launch_bounds__(256) void prep_kernel(
    const float* __restrict__ x,
    const float* __restrict__ w3, const float* __restrict__ b3, const float* __restrict__ dw3,
    const float* __restrict__ g3, const float* __restrict__ be3, const float* __restrict__ m3, const float* __restrict__ v3,
    const float* __restrict__ w5, const float* __restrict__ b5, const float* __restrict__ dw5,
    const float* __restrict__ g5, const float* __restrict__ be5, const float* __restrict__ m5, const float* __restrict__ v5,
    const float* __restrict__ w7, const float* __restrict__ b7, const float* __restrict__ dw7,
    const float* __restrict__ g7, const float* __restrict__ be7, const float* __restrict__ m7, const float* __restrict__ v7,
    const float* __restrict__ wpw,
    const float* __restrict__ gp, const float* __restrict__ bp, const float* __restrict__ mp, const float* __restrict__ vp,
    float* __restrict__ ws)
{
    __shared__ u16 sT[64 * 104];
    u16* bf = (u16*)(ws + FP32_END);
    const int tid = threadIdx.x;

    if (blockIdx.x < 256) {                 // ---- xtpad interior ----
        const int b = blockIdx.x >> 6, h = blockIdx.x & 63;
        const float* xb = x + (((size_t)b * Cc) << 12) + (h << 6);
#pragma unroll
        for (int it = 0; it < 24; ++it) {
            int j = tid + it * 256;
            int c = j >> 6, p = j & 63;
            sT[p * 104 + c] = f2h(xb[((size_t)c << 12) + p]);
        }
        __syncthreads();
        u16* dst = bf + BF_XTPAD + ((size_t)(b * 66 + h + 1) * 66 + 1) * 96;
#pragma unroll
        for (int it = 0; it < 6; ++it) {
            int j = tid + it * 256;
            int pos = j / 24, c4 = j % 24;
            const u16* s = &sT[pos * 104 + c4 * 4];
            *(uint2*)(dst + pos * 96 + c4 * 4) = make_uint2(
                (unsigned)s[0] | ((unsigned)s[1] << 16),
                (unsigned)s[2] | ((unsigned)s[3] << 16));
        }
        return;
    }

    int i = (blockIdx.x - 256) * 256 + tid;
    if (i < 165888) {                       // WOF frag-linear f16
        int f = i / 13824, r = i % 13824;
        int s = r >> 9, l = r & 511;
        int lane = l >> 3, j = l & 7;
        int o = f * 16 + (lane & 15);
        int k = s * 32 + (lane >> 4) * 8 + j;
        int tap = k / 96, c = k % 96;
        float v = 0.f;
        if (o < 18)       v = w3[o * 864 + c * 9 + tap];
        else if (o < 68)  v = w5[(o - 18) * 864 + c * 9 + tap];
        else if (o < 166) v = w7[(o - 68) * 864 + c * 9 + tap];
        bf[BF_WOF + i] = f2h(v);
        return;
    }
    int j = i - 165888;
    if (j < 55296) {                        // WPW frag-linear f16
        int f = j / 4608, r = j % 4608;
        int s = r >> 9, l = r & 511;
        int lane = l >> 3, jj = l & 7;
        int o = f * 16 + (lane & 15);
        int k = s * 32 + (lane >> 4) * 8 + jj;
        bf[BF_WPW + j] = f2h(wpw[o * C3 + k]);
        return;
    }
    j -= 55296;
    if (j < 14112) {                        // wdwT [3][49][96] fp32
        int ksel = j / 4704, rem = j % 4704;
        int t = rem / 96, c = rem % 96;
        int K2 = (ksel == 0) ? 9 : (ksel == 1) ? 25 : 49;
        const float* dw = (ksel == 0) ? dw3 : (ksel == 1) ? dw5 : dw7;
        ws[OFF_WDWT + j] = (t < K2) ? dw[c * K2 + t] : 0.f;
        return;
    }
    j -= 14112;
    if (j < 192) {                          // bcat
        float v = 0.f;
        if (j < 18)       v = b3[j];
        else if (j < 68)  v = b5[j - 18];
        else if (j < 166) v = b7[j - 68];
        ws[OFF_BCAT + j] = v;
        return;
    }
    j -= 192;
    if (j < C3) {                           // sbr
        int ks = j / Cc, c = j % Cc;
        const float* g = (ks == 0) ? g3 : (ks == 1) ? g5 : g7;
        const float* v = (ks == 0) ? v3 : (ks == 1) ? v5 : v7;
        ws[OFF_SBR + j] = g[c] / sqrtf(v[c] + 1e-5f);
        return;
    }
    j -= C3;
    if (j < C3) {                           // hbr
        int ks = j / Cc, c = j % Cc;
        const float* g = (ks == 0) ? g3 : (ks == 1) ? g5 : g7;
        const float* v = (ks == 0) ? v3 : (ks == 1) ? v5 : v7;
        const float* be = (ks == 0) ? be3 : (ks == 1) ? be5 : be7;
        const float* m = (ks == 0) ? m3 : (ks == 1) ? m5 : m7;
        float inv = g[c] / sqrtf(v[c] + 1e-5f);
        ws[OFF_HBR + j] = be[c] - m[c] * inv;
        return;
    }
    j -= C3;
    if (j < Oo) { ws[OFF_SPW + j] = gp[j] / sqrtf(vp[j] + 1e-5f); return; }
    j -= Oo;
    if (j < Oo) {
        float inv = gp[j] / sqrtf(vp[j] + 1e-5f);
        ws[OFF_HPW + j] = bp[j] - mp[j] * inv;
        return;
    }
    j -= Oo;
    if (j < 24960) {                        // halo zero
        int c4 = j % 24, rem = j / 24;
        int cell = rem % 260, bb = rem / 260;
        int row, col;
        if (cell < 66)       { row = 0;  col = cell; }
        else if (cell < 132) { row = 65; col = cell - 66; }
        else if (cell < 196) { row = cell - 132 + 1; col = 0; }
        else                 { row = cell - 196 + 1; col = 65; }
        u16* dst = bf + BF_XTPAD + ((size_t)(bb * 66 + row) * 66 + col) * 96 + c4 * 4;
        *(uint2*)dst = make_uint2(0u, 0u);
        return;
    }
}

// ---------------- mega kernel: offconv -> sampling -> depthwise -> pwconv, fully fused ----------------
// XCD-swizzled 1-D grid; batch image L2-resident per XCD.
// Round 8 = the proven 192-thread VMEM-gather base (r0/r3/r5, all ~73 us) with the
// per-tap instruction count minimized:
//   - single 16-B uint4 table slot per (tap,pos) -> ONE ds_read_b128 (r3/r5 used
//     two reads to save LDS that grid-capped occupancy made worthless)
//   - flagless gather (r4-validated): +1 neighbor always in-bounds via zero halo;
//     at clip the corresponding bilinear weight is exactly 0
//   - no wave-3 rebalance / sP1 (r5 measured it neutral; removes a barrier)
// r6/r7 (LDS staging) refuted: bank conflicts + halved occupancy cost more than
// the L2 traffic they saved.
__global__ __launch_bounds__(256, 4) void mega_kernel(
    const float* __restrict__ ws, float* __restrict__ out)
{
    __shared__ __align__(16) unsigned char shA[21248];  // sX (11232 B) / sWI (21248 B)
    __shared__ float regB[3072];                        // 12288 B: soff / ytile
    u16* sX = (u16*)shA;
    uint4* sWI = (uint4*)shA;                           // [1328] 16 B slots
    float* soff = regB;
    u16* ytile = (u16*)regB;

    const u16* bf = (const u16*)(ws + FP32_END);
    const u16* xp = bf + BF_XTPAD;
    const int tid = threadIdx.x;
    const int lane = tid & 63, wid = tid >> 6;
    const int lane15 = lane & 15, quad = lane >> 4;

    // XCD-aware swizzle: 1024 blocks -> (batch, tile)
    const int bx = blockIdx.x;
    const int xcd = bx & 7;
    const int b = xcd >> 1;                       // 2 XCDs per batch
    const int tile = ((bx >> 3) << 1) + (xcd & 1); // 0..255, sequential rows per XCD
    const int p0 = tile * 16;
    const int h = p0 >> 6;                 // image row
    const int w0 = p0 & 63;                // start col (0/16/32/48)

    // ---- phase 1: load 3-row x 18-col patch into sX ----
    {
        const u16* src = xp + ((size_t)(b * 66 + h) * 66 + w0) * 96;
        for (int j = tid; j < 1296; j += 256) {       // 3*18*24 uint2 chunks
            int r = j / 432;
            int rem = j % 432;
            int col = rem / 24, c4 = rem % 24;
            uint2 v = *(const uint2*)(src + ((size_t)(r * 66 + col)) * 96 + c4 * 4);
            *(uint2*)(&sX[(r * 18 + col) * 104 + c4 * 4]) = v;
        }
    }
    __syncthreads();

    // ---- phase 2: offset conv MFMA (M=192 as 12 frags / 4 waves, N=16, K=864) ----
    {
        const u16* wof = bf + BF_WOF;
        f32x4 acc[3];
#pragma unroll
        for (int ff = 0; ff < 3; ++ff) acc[ff] = (f32x4){0.f, 0.f, 0.f, 0.f};
#pragma unroll
        for (int tap = 0; tap < 9; ++tap) {
            const int ky2 = tap / 3, kx2 = tap % 3;
            const u16* brow = &sX[(ky2 * 18 + kx2 + lane15) * 104 + quad * 8];
#pragma unroll
            for (int cc = 0; cc < 3; ++cc) {
                f16x8 bb = *(const f16x8*)(brow + cc * 32);
                const int s = tap * 3 + cc;
#pragma unroll
                for (int ff = 0; ff < 3; ++ff) {
                    const int f = wid * 3 + ff;
                    f16x8 a = *(const f16x8*)(wof + ((size_t)(f * 27 + s) * 64 + lane) * 8);
                    acc[ff] = __builtin_amdgcn_mfma_f32_16x16x32_f16(a, bb, acc[ff], 0, 0, 0);
                }
            }
        }
        const float* bcat = ws + OFF_BCAT;
#pragma unroll
        for (int ff = 0; ff < 3; ++ff) {
#pragma unroll
            for (int r = 0; r < 4; ++r) {
                int co = (wid * 3 + ff) * 16 + quad * 4 + r;
                soff[co * 16 + lane15] = acc[ff][r] + bcat[co];
            }
        }
    }
    __syncthreads();   // sX reads done; soff complete

    // ---- phase 3: bilinear weight/offset table (83 taps x 16 pos) -> sWI (clobbers sX) ----
    for (int i = tid; i < 1328; i += 256) {
        int gt = i >> 4, q = i & 15;
        int K, K2, R, tb, t;
        if (gt < 9)       { K = 3; K2 = 9;  R = 1; tb = 0;  t = gt; }
        else if (gt < 34) { K = 5; K2 = 25; R = 2; tb = 18; t = gt - 9; }
        else              { K = 7; K2 = 49; R = 3; tb = 68; t = gt - 34; }
        int ky = t / K - R, kx = t % K - R;
        float dy = soff[(tb + t) * 16 + q];
        float dx = soff[(tb + K2 + t) * 16 + q];
        float py = fminf(fmaxf((float)(h + ky) + dy, 0.f), 63.f);
        float px = fminf(fmaxf((float)(w0 + q + kx) + dx, 0.f), 63.f);
        float fy = floorf(py), fx = floorf(px);
        int y0 = (int)fy, x0 = (int)fx;
        float wy = py - fy, wx = px - fx;
        float w11 = wy * wx;
        float w10 = wy - w11;
        float w01 = wx - w11;
        float w00 = 1.f - wy - wx + w11;
        // +1 neighbor always valid: at clip (y0==63 / x0==63) its weight is 0 and
        // padded row/col 64 exists (zero halo) -> no flags needed.
        unsigned wA = h2u(__floats2half2_rn(w00, w01));
        unsigned wB = h2u(__floats2half2_rn(w10, w11));
        unsigned o00 = (unsigned)((y0 + 1) * 66 + (x0 + 1)) * 192u;   // byte offset
        sWI[i] = make_uint4(wA, wB, o00, 0u);
    }
    __syncthreads();   // soff consumed; sWI ready

    // ---- phase 4: gather + depthwise + BN + ReLU -> ytile (clobbers soff) ----
#define TAP8(ACC, GT, Q, XCB, WDP) { \
    const uint4 e = sWI[((GT) << 4) + (Q)]; \
    const __half2 wAh = u2h(e.x), wBh = u2h(e.y); \
    const __half2 w00b = __low2half2(wAh), w01b = __high2half2(wAh); \
    const __half2 w10b = __low2half2(wBh), w11b = __high2half2(wBh); \
    const char* pb = (XCB) + e.z; \
    const uint4 u00 = *(const uint4*)(pb); \
    const uint4 u01 = *(const uint4*)(pb + 192); \
    const uint4 u10 = *(const uint4*)(pb + 12672); \
    const uint4 u11 = *(const uint4*)(pb + 12864); \
    const float4 wda = *(const float4*)(WDP); \
    const float4 wdb = *(const float4*)((WDP) + 4); \
    const unsigned a00[4] = {u00.x, u00.y, u00.z, u00.w}; \
    const unsigned a01[4] = {u01.x, u01.y, u01.z, u01.w}; \
    const unsigned a10[4] = {u10.x, u10.y, u10.z, u10.w}; \
    const unsigned a11[4] = {u11.x, u11.y, u11.z, u11.w}; \
    const float wd8[8] = {wda.x, wda.y, wda.z, wda.w, wdb.x, wdb.y, wdb.z, wdb.w}; \
    _Pragma("unroll") \
    for (int d = 0; d < 4; ++d) { \
        __half2 v = __hmul2(w00b, u2h(a00[d])); \
        v = __hfma2(w01b, u2h(a01[d]), v); \
        v = __hfma2(w10b, u2h(a10[d]), v); \
        v = __hfma2(w11b, u2h(a11[d]), v); \
        ACC[2 * d]     = fmaf(wd8[2 * d],     __low2float(v),  ACC[2 * d]); \
        ACC[2 * d + 1] = fmaf(wd8[2 * d + 1], __high2float(v), ACC[2 * d + 1]); \
    } }

#define BN_STORE(ACC, CB, Q) { \
    const float4 sa = *(const float4*)(ws + OFF_SBR + (CB)); \
    const float4 sb = *(const float4*)(ws + OFF_SBR + (CB) + 4); \
    const float4 ha = *(const float4*)(ws + OFF_HBR + (CB)); \
    const float4 hb = *(const float4*)(ws + OFF_HBR + (CB) + 4); \
    const float ss8[8] = {sa.x, sa.y, sa.z, sa.w, sb.x, sb.y, sb.z, sb.w}; \
    const float hh8[8] = {ha.x, ha.y, ha.z, ha.w, hb.x, hb.y, hb.z, hb.w}; \
    unsigned rr[4]; \
    _Pragma("unroll") \
    for (int d = 0; d < 4; ++d) { \
        float lo = fmaxf(fmaf(ACC[2 * d],     ss8[2 * d],     hh8[2 * d]),     0.f); \
        float hi = fmaxf(fmaf(ACC[2 * d + 1], ss8[2 * d + 1], hh8[2 * d + 1]), 0.f); \
        rr[d] = h2u(__floats2half2_rn(lo, hi)); \
    } \
    *(uint4*)(ytile + (Q) * 296 + (CB)) = make_uint4(rr[0], rr[1], rr[2], rr[3]); }

    if (tid < 192) {
        const int c8 = tid % 12;
        const int q  = tid / 12;            // 0..15
        const int c = c8 * 8;
        const u16* xh = xp + (size_t)b * 66 * 66 * 96;
        const char* xcb = (const char*)xh + c * 2;

        {   // seg0 (3x3): taps 0..8
            float acc[8] = {0.f, 0.f, 0.f, 0.f, 0.f, 0.f, 0.f, 0.f};
            const float* wdT = ws + OFF_WDWT + c;
            for (int gt = 0; gt < 9; ++gt)
                TAP8(acc, gt, q, xcb, wdT + gt * 96);
            BN_STORE(acc, c, q);
        }
        {   // seg1 (5x5): taps 9..33
            float acc[8] = {0.f, 0.f, 0.f, 0.f, 0.f, 0.f, 0.f, 0.f};
            const float* wdT = ws + OFF_WDWT + 4704 + c;
            for (int gt = 9; gt < 34; ++gt)
                TAP8(acc, gt, q, xcb, wdT + (gt - 9) * 96);
            BN_STORE(acc, 96 + c, q);
        }
        {   // seg2 (7x7): taps 34..82
            float acc[8] = {0.f, 0.f, 0.f, 0.f, 0.f, 0.f, 0.f, 0.f};
            const float* wdT = ws + OFF_WDWT + 9408 + c;
            for (int gt = 34; gt < 83; ++gt)
                TAP8(acc, gt, q, xcb, wdT + (gt - 34) * 96);
            BN_STORE(acc, 192 + c, q);
        }
    }
    __syncthreads();   // sWI consumed; ytile ready

    // ---- phase 5: pointwise MFMA (M=192 as 12 frags / 4 waves, N=16, K=288) + BN + ReLU ----
    {
        const u16* wpw = bf + BF_WPW;
        f32x4 acc[3];
#pragma unroll
        for (int ff = 0; ff < 3; ++ff) acc[ff] = (f32x4){0.f, 0.f, 0.f, 0.f};
        const u16* brow = &ytile[lane15 * 296 + quad * 8];
#pragma unroll
        for (int s = 0; s < 9; ++s) {
            f16x8 bb = *(const f16x8*)(brow + s * 32);
#pragma unroll
            for (int ff = 0; ff < 3; ++ff) {
                const int f = wid * 3 + ff;
                f16x8 a = *(const f16x8*)(wpw + ((size_t)(f * 9 + s) * 64 + lane) * 8);
                acc[ff] = __builtin_amdgcn_mfma_f32_16x16x32_f16(a, bb, acc[ff], 0, 0, 0);
            }
        }
        const float* spw = ws + OFF_SPW;
        const float* hpw = ws + OFF_HPW;
        const int p = p0 + lane15;
#pragma unroll
        for (int ff = 0; ff < 3; ++ff) {
#pragma unroll
            for (int r = 0; r < 4; ++r) {
                int o = (wid * 3 + ff) * 16 + quad * 4 + r;
                out[(((size_t)(b * Oo + o)) << 12) + p] =
                    fmaxf(fmaf(acc[ff][r], spw[o], hpw[o]), 0.f);
            }
        }
    }
}

extern "C" void kernel_launch(void* const* d_in, const int* in_sizes, int n_in,
                              void* d_out, int out_size, void* d_ws, size_t ws_size,
                              hipStream_t stream)
{
    const float* x     = (const float*)d_in[0];
    const float* w3    = (const float*)d_in[1];
    const float* b3    = (const float*)d_in[2];
    const float* dw3   = (const float*)d_in[3];
    const float* g3    = (const float*)d_in[4];
    const float* be3   = (const float*)d_in[5];
    const float* m3    = (const float*)d_in[6];
    const float* v3    = (const float*)d_in[7];
    const float* w5    = (const float*)d_in[8];
    const float* b5    = (const float*)d_in[9];
    const float* dw5   = (const float*)d_in[10];
    const float* g5    = (const float*)d_in[11];
    const float* be5   = (const float*)d_in[12];
    const float* m5    = (const float*)d_in[13];
    const float* v5    = (const float*)d_in[14];
    const float* w7    = (const float*)d_in[15];
    const float* b7    = (const float*)d_in[16];
    const float* dw7   = (const float*)d_in[17];
    const float* g7    = (const float*)d_in[18];
    const float* be7   = (const float*)d_in[19];
    const float* m7    = (const float*)d_in[20];
    const float* v7    = (const float*)d_in[21];
    const float* wpw   = (const float*)d_in[22];
    const float* gp    = (const float*)d_in[23];
    const float* bp    = (const float*)d_in[24];
    const float* mp    = (const float*)d_in[25];
    const float* vp    = (const float*)d_in[26];

    float* ws = (float*)d_ws;
    float* out = (float*)d_out;

    {   // 1) prep + xtpad (merged)
        prep_kernel<<<256 + PREP_BLK, 256, 0, stream>>>(
            x,
            w3, b3, dw3, g3, be3, m3, v3,
            w5, b5, dw5, g5, be5, m5, v5,
            w7, b7, dw7, g7, be7, m7, v7,
            wpw, gp, bp, mp, vp, ws);
    }
    {   // 2) fully fused pipeline, XCD-swizzled 1-D grid
        mega_kernel<<<1024, 256, 0, stream>>>(ws, out);
    }
}